// Round 4
// baseline (700.380 us; speedup 1.0000x reference)
//
#include <hip/hip_runtime.h>
#include <hip/hip_bf16.h>
#include <hip/hip_cooperative_groups.h>

namespace cg = cooperative_groups;

#define N_NODES 100000
#define NPB 512                       // nodes per fused block
#define FGRID ((N_NODES + NPB - 1) / NPB)   // 196 blocks <= 256 CUs (1 block/CU)

typedef unsigned short ushort_t;
typedef __attribute__((ext_vector_type(8))) short short8;
typedef __attribute__((ext_vector_type(4))) float f32x4;

// ---------------------------------------------------------------------------
// helpers
// ---------------------------------------------------------------------------
static __device__ __forceinline__ ushort_t f2bf(float f) {
    unsigned u = __float_as_uint(f);
    unsigned r = u + 0x7FFFu + ((u >> 16) & 1u);   // round-to-nearest-even
    return (ushort_t)(r >> 16);
}
static __device__ __forceinline__ float bf2f(ushort_t h) {
    return __uint_as_float(((unsigned)h) << 16);
}

// split 8 contiguous fp32 into hi/lo bf16 fragments
static __device__ __forceinline__ void split8(const float* __restrict__ xp,
                                              short8& hi, short8& lo) {
    float4 x0 = *(const float4*)xp;
    float4 x1 = *(const float4*)(xp + 4);
    float xs[8] = {x0.x, x0.y, x0.z, x0.w, x1.x, x1.y, x1.z, x1.w};
    #pragma unroll
    for (int j = 0; j < 8; ++j) {
        ushort_t h = f2bf(xs[j]);
        hi[j] = (short)h;
        lo[j] = (short)f2bf(xs[j] - bf2f(h));
    }
}

// unpack-accumulate one u32 (2 bf16) into two fp32 accumulators
static __device__ __forceinline__ void acc_u32(unsigned w, float& a0, float& a1) {
    a0 += __uint_as_float(w << 16);
    a1 += __uint_as_float(w & 0xFFFF0000u);
}

// ---------------------------------------------------------------------------
// CSR build: histogram -> 3-phase scan -> bucket-binning -> exclusive scatter
// ---------------------------------------------------------------------------

__global__ __launch_bounds__(256) void scan_partial_sums(const int* __restrict__ deg,
                                                         int* __restrict__ partials, int N) {
    __shared__ int wsums[4];
    int tid = threadIdx.x, lane = tid & 63, wv = tid >> 6;
    int i0 = blockIdx.x * 1024 + tid * 4;
    int s = 0;
    #pragma unroll
    for (int j = 0; j < 4; ++j) {
        int i = i0 + j;
        if (i < N) s += deg[i];
    }
    #pragma unroll
    for (int off = 32; off > 0; off >>= 1) s += __shfl_xor(s, off, 64);
    if (lane == 0) wsums[wv] = s;
    __syncthreads();
    if (tid == 0)
        partials[blockIdx.x] = wsums[0] + wsums[1] + wsums[2] + wsums[3];
}

__global__ __launch_bounds__(256) void scan_partials(int* __restrict__ partials, int NB,
                                                     int* __restrict__ row_ptr, int N) {
    __shared__ int wsums[4];
    int tid = threadIdx.x, lane = tid & 63, wv = tid >> 6;
    int v = (tid < NB) ? partials[tid] : 0;
    int x = v;
    #pragma unroll
    for (int off = 1; off < 64; off <<= 1) {
        int y = __shfl_up(x, off, 64);
        if (lane >= off) x += y;
    }
    if (lane == 63) wsums[wv] = x;
    __syncthreads();
    int woff = 0;
    for (int w = 0; w < wv; ++w) woff += wsums[w];
    int incl = x + woff;
    if (tid < NB) partials[tid] = incl - v;          // exclusive
    if (tid == NB - 1) row_ptr[N] = incl;            // grand total
}

__global__ __launch_bounds__(256) void scan_emit(const int* __restrict__ deg,
                                                 const int* __restrict__ partials,
                                                 int* __restrict__ row_ptr,
                                                 int* __restrict__ cursor,
                                                 float* __restrict__ inv_deg,
                                                 int* __restrict__ gcur, int N) {
    __shared__ int wsums[4];
    int tid = threadIdx.x, lane = tid & 63, wv = tid >> 6;
    int i0 = blockIdx.x * 1024 + tid * 4;
    int d[4];
    #pragma unroll
    for (int j = 0; j < 4; ++j) {
        int i = i0 + j;
        d[j] = (i < N) ? deg[i] : 0;
    }
    int s = d[0] + d[1] + d[2] + d[3];
    int x = s;
    #pragma unroll
    for (int off = 1; off < 64; off <<= 1) {
        int y = __shfl_up(x, off, 64);
        if (lane >= off) x += y;
    }
    if (lane == 63) wsums[wv] = x;
    __syncthreads();
    int woff = 0;
    for (int w = 0; w < wv; ++w) woff += wsums[w];
    int run = partials[blockIdx.x] + woff + x - s;   // exclusive prefix of elem i0
    #pragma unroll
    for (int j = 0; j < 4; ++j) {
        int i = i0 + j;
        if (i < N) {
            row_ptr[i] = run;
            cursor[i]  = run;
            inv_deg[i] = 1.0f / (float)(d[j] > 0 ? d[j] : 1);
            if ((i & 255) == 0) gcur[i >> 8] = run;   // bucket staging base
            run += d[j];
        }
    }
}

#define MAXBUCK 512
__global__ __launch_bounds__(256) void bin_pairs(const int* __restrict__ src,
                                                 const int* __restrict__ dst,
                                                 int* __restrict__ gcur,
                                                 long long* __restrict__ staged,
                                                 int E, int NBUCK, int C) {
    __shared__ int cnt[MAXBUCK];
    int tid = threadIdx.x;
    int e0 = blockIdx.x * C;
    int e1 = min(e0 + C, E);
    for (int b = tid; b < NBUCK; b += 256) cnt[b] = 0;
    __syncthreads();
    for (int e = e0 + tid; e < e1; e += 256) {
        int d = __builtin_nontemporal_load(&dst[e]);
        atomicAdd(&cnt[d >> 8], 1);
    }
    __syncthreads();
    for (int b = tid; b < NBUCK; b += 256) {
        int c = cnt[b];
        cnt[b] = (c > 0) ? atomicAdd(&gcur[b], c) : 0;   // now LDS cursor = global pos
    }
    __syncthreads();
    for (int e = e0 + tid; e < e1; e += 256) {
        int d = __builtin_nontemporal_load(&dst[e]);
        int s = __builtin_nontemporal_load(&src[e]);
        int p = atomicAdd(&cnt[d >> 8], 1);
        staged[p] = ((long long)d << 32) | (unsigned)s;   // hi=dst, lo=src
    }
}

__global__ __launch_bounds__(256) void scatter_bucket(const long long* __restrict__ staged,
                                                      const int* __restrict__ row_ptr,
                                                      int* __restrict__ cursor,
                                                      int* __restrict__ edge_src,
                                                      int N) {
    int b = blockIdx.x;
    int lo = b << 8;
    int hiN = min((b + 1) << 8, N);
    int gstart = row_ptr[lo];
    int gend   = row_ptr[hiN];
    for (int p = gstart + threadIdx.x; p < gend; p += 256) {
        long long pr = __builtin_nontemporal_load(&staged[p]);
        int d = (int)(pr >> 32);
        int s = (int)(pr & 0xFFFFFFFFll);
        int pos = atomicAdd(&cursor[d], 1);
        edge_src[pos] = s;
    }
}

// ---------------------------------------------------------------------------
// Weight pre-pack (6 matrices) MERGED with degree histogram
// ---------------------------------------------------------------------------
__global__ __launch_bounds__(256) void pack_hist(
        const float* __restrict__ W0, const float* __restrict__ W1,
        const float* __restrict__ W2, const float* __restrict__ W3,
        const float* __restrict__ W4, const float* __restrict__ W5,
        ushort_t* H0, ushort_t* L0, ushort_t* H1, ushort_t* L1,
        ushort_t* H2, ushort_t* L2, ushort_t* H3, ushort_t* L3,
        ushort_t* H4, ushort_t* L4, ushort_t* H5, ushort_t* L5,
        const int* __restrict__ dst, int* __restrict__ deg, int E) {
    int b = blockIdx.x;
    if (b >= 28) {
        int e = (b - 28) * 256 + threadIdx.x;
        if (e < E) atomicAdd(&deg[__builtin_nontemporal_load(&dst[e])], 1);
        return;
    }
    const float* W; ushort_t* Hi; ushort_t* Lo; int K, NS, base;
    if (b < 8)       { W = W0; Hi = H0; Lo = L0; K = 128; NS = 128; base = 0;  }
    else if (b < 16) { W = W1; Hi = H1; Lo = L1; K = 128; NS = 128; base = 8;  }
    else if (b < 20) { W = W2; Hi = H2; Lo = L2; K = 128; NS = 64;  base = 16; }
    else if (b < 24) { W = W3; Hi = H3; Lo = L3; K = 128; NS = 64;  base = 20; }
    else if (b < 26) { W = W4; Hi = H4; Lo = L4; K = 64;  NS = 64;  base = 24; }
    else             { W = W5; Hi = H5; Lo = L5; K = 64;  NS = 64;  base = 26; }
    int tid = (b - base) * 256 + threadIdx.x;
    if (tid >= (K * NS) / 8) return;
    int l  = tid & 63;
    int fl = tid >> 6;
    int NT = NS / 16;
    int t = fl % NT, s = fl / NT;
    ushort_t hs[8], ls[8];
    #pragma unroll
    for (int j = 0; j < 8; ++j) {
        int k = s * 32 + (l >> 4) * 8 + j;
        int n = t * 16 + (l & 15);
        float w = W[(size_t)k * NS + n];
        ushort_t h = f2bf(w);
        hs[j] = h;
        ls[j] = f2bf(w - bf2f(h));
    }
    #pragma unroll
    for (int j = 0; j < 8; ++j) {
        Hi[(size_t)tid * 8 + j] = hs[j];
        Lo[(size_t)tid * 8 + j] = ls[j];
    }
}

// ---------------------------------------------------------------------------
// Fused per-layer phases (device functions used by the cooperative kernel).
//
// gemm_phase: 512 local rows, 64 output cols (tiles tileBase..tileBase+3 of a
// pack with NTW n-tiles). S (+bias, fp32) -> LDS Sl[row][64]; Z (bf16) ->
// global Zg[N][64]. 8 waves x 2 passes x 32-row MFMA tiles. Split-bf16
// (hi/lo) 3-MFMA products for fp32-grade S/Z, identical math to R0-R3.
// ---------------------------------------------------------------------------
template <int K, int NTW>
static __device__ __forceinline__ void gemm_phase(
        const float* __restrict__ X,
        const ushort_t* __restrict__ BsHi, const ushort_t* __restrict__ BsLo,
        const ushort_t* __restrict__ BnHi, const ushort_t* __restrict__ BnLo,
        const float* __restrict__ bias, int colBase, int tileBase,
        float* __restrict__ Sl, ushort_t* __restrict__ Zg,
        float* __restrict__ bufZ, int nodeBase, int N, int tid) {
    constexpr int KS = K / 32;
    int lane = tid & 63, w = tid >> 6;
    int rIn = lane & 15, q = lane >> 4;
    float* bufZw = bufZ + w * 640;     // per-wave private 32x20 transpose buffer
    #pragma unroll
    for (int p = 0; p < 2; ++p) {
        int rowBase = p * 256 + w * 32;
        int gmBase = nodeBase + rowBase;
        short8 Ahi[KS][2], Alo[KS][2];
        #pragma unroll
        for (int s = 0; s < KS; ++s) {
            #pragma unroll
            for (int mt = 0; mt < 2; ++mt) {
                int gm = gmBase + mt * 16 + rIn;
                if (gm < N) {
                    split8(&X[(size_t)gm * K + s * 32 + q * 8], Ahi[s][mt], Alo[s][mt]);
                } else {
                    #pragma unroll
                    for (int j = 0; j < 8; ++j) { Ahi[s][mt][j] = 0; Alo[s][mt][j] = 0; }
                }
            }
        }
        #pragma unroll
        for (int t = 0; t < 4; ++t) {
            f32x4 aS0 = {0.f, 0.f, 0.f, 0.f}, aS1 = {0.f, 0.f, 0.f, 0.f};
            f32x4 aZ0 = {0.f, 0.f, 0.f, 0.f}, aZ1 = {0.f, 0.f, 0.f, 0.f};
            #pragma unroll
            for (int s = 0; s < KS; ++s) {
                size_t fo = ((size_t)(s * NTW + tileBase + t) * 64 + lane) * 8;
                short8 bsh = *(const short8*)&BsHi[fo];
                short8 bsl = *(const short8*)&BsLo[fo];
                short8 bnh = *(const short8*)&BnHi[fo];
                short8 bnl = *(const short8*)&BnLo[fo];
                aS0 = __builtin_amdgcn_mfma_f32_16x16x32_bf16(Ahi[s][0], bsh, aS0, 0, 0, 0);
                aS0 = __builtin_amdgcn_mfma_f32_16x16x32_bf16(Alo[s][0], bsh, aS0, 0, 0, 0);
                aS0 = __builtin_amdgcn_mfma_f32_16x16x32_bf16(Ahi[s][0], bsl, aS0, 0, 0, 0);
                aS1 = __builtin_amdgcn_mfma_f32_16x16x32_bf16(Ahi[s][1], bsh, aS1, 0, 0, 0);
                aS1 = __builtin_amdgcn_mfma_f32_16x16x32_bf16(Alo[s][1], bsh, aS1, 0, 0, 0);
                aS1 = __builtin_amdgcn_mfma_f32_16x16x32_bf16(Ahi[s][1], bsl, aS1, 0, 0, 0);
                aZ0 = __builtin_amdgcn_mfma_f32_16x16x32_bf16(Ahi[s][0], bnh, aZ0, 0, 0, 0);
                aZ0 = __builtin_amdgcn_mfma_f32_16x16x32_bf16(Alo[s][0], bnh, aZ0, 0, 0, 0);
                aZ0 = __builtin_amdgcn_mfma_f32_16x16x32_bf16(Ahi[s][0], bnl, aZ0, 0, 0, 0);
                aZ1 = __builtin_amdgcn_mfma_f32_16x16x32_bf16(Ahi[s][1], bnh, aZ1, 0, 0, 0);
                aZ1 = __builtin_amdgcn_mfma_f32_16x16x32_bf16(Alo[s][1], bnh, aZ1, 0, 0, 0);
                aZ1 = __builtin_amdgcn_mfma_f32_16x16x32_bf16(Ahi[s][1], bnl, aZ1, 0, 0, 0);
            }
            // S + bias direct to LDS (empirical acc layout: elem r of lane ->
            // row = q*4+r (+16 for aS1), col = t*16 + rIn; verified R0-R3)
            float bv = bias[colBase + t * 16 + rIn];
            #pragma unroll
            for (int r = 0; r < 4; ++r) {
                Sl[(rowBase + q * 4 + r) * 64 + t * 16 + rIn]      = aS0[r] + bv;
                Sl[(rowBase + 16 + q * 4 + r) * 64 + t * 16 + rIn] = aS1[r] + bv;
                bufZw[(q * 4 + r) * 20 + rIn]      = aZ0[r];
                bufZw[(16 + q * 4 + r) * 20 + rIn] = aZ1[r];
            }
            // Z: wave-private LDS transpose -> vector bf16 global stores
            int row = lane >> 2, cq = lane & 3;
            int col = t * 16 + cq * 4;
            #pragma unroll
            for (int half = 0; half < 2; ++half) {
                int gm = gmBase + half * 16 + row;
                float4 z = *(float4*)&bufZw[(half * 16 + row) * 20 + cq * 4];
                if (gm < N) {
                    uint2 o2;
                    o2.x = (unsigned)f2bf(z.x) | ((unsigned)f2bf(z.y) << 16);
                    o2.y = (unsigned)f2bf(z.z) | ((unsigned)f2bf(z.w) << 16);
                    *(uint2*)&Zg[(size_t)gm * 64 + col] = o2;
                }
            }
        }
    }
}

// ---------------------------------------------------------------------------
// agg_phase: 8 lanes/node (64-wide rows), 64 nodes per 512-thread pass,
// 8 passes cover the block's 512 nodes. Gathers 128B Z rows (uint4/lane),
// cooperative edge-index loads + shfl broadcast, S read from LDS.
// ACT: 0 = relu -> outp[n*outStride + outColBase + ...]; 1 = softmax (D=64).
// No early returns (cooperative kernel needs uniform grid.sync control flow).
// ---------------------------------------------------------------------------
template <int ACT>
static __device__ __forceinline__ void agg_phase(
        const float* __restrict__ Sl,
        const ushort_t* __restrict__ Zg,
        const int* __restrict__ row_ptr, const int* __restrict__ edge_src,
        const float* __restrict__ invd,
        float* __restrict__ outp, int outStride, int outColBase,
        int nodeBase, int N, int tid) {
    int g = tid >> 3, fl = tid & 7;
    const char* zlane = (const char*)Zg + fl * 16;
    #pragma unroll 1
    for (int pass = 0; pass < 8; ++pass) {
        int nl = pass * 64 + g;
        int n = nodeBase + nl;
        bool act = (n < N);
        int beg = 0, end = 0;
        float id = 0.f;
        if (act) { beg = row_ptr[n]; end = row_ptr[n + 1]; id = invd[n]; }
        float acc[2][8];
        #pragma unroll
        for (int i = 0; i < 8; ++i) { acc[0][i] = 0.f; acc[1][i] = 0.f; }
        for (int j = beg; j < end; j += 8) {
            int je = j + fl;
            int myS = (je < end) ? __builtin_nontemporal_load(&edge_src[je]) : -1;
            uint4 u[8];
            #pragma unroll
            for (int k = 0; k < 8; ++k) {
                int s = __shfl(myS, k, 8);
                u[k] = make_uint4(0u, 0u, 0u, 0u);
                if (s >= 0)
                    u[k] = *(const uint4*)(zlane + ((size_t)((unsigned)s) << 7));
            }
            #pragma unroll
            for (int k = 0; k < 8; ++k) {
                acc_u32(u[k].x, acc[k & 1][0], acc[k & 1][1]);
                acc_u32(u[k].y, acc[k & 1][2], acc[k & 1][3]);
                acc_u32(u[k].z, acc[k & 1][4], acc[k & 1][5]);
                acc_u32(u[k].w, acc[k & 1][6], acc[k & 1][7]);
            }
        }
        if (act) {
            const f32x4* Sp = (const f32x4*)(Sl + nl * 64 + fl * 8);
            f32x4 s40 = Sp[0], s41 = Sp[1];
            float v[8];
            #pragma unroll
            for (int i = 0; i < 4; ++i) {
                v[i]     = s40[i] + id * (acc[0][i]     + acc[1][i]);
                v[4 + i] = s41[i] + id * (acc[0][4 + i] + acc[1][4 + i]);
            }
            float4* Op = (float4*)(outp + (size_t)n * outStride + outColBase) + fl * 2;
            if constexpr (ACT == 0) {
                float4 o0, o1;
                o0.x = fmaxf(v[0], 0.f); o0.y = fmaxf(v[1], 0.f);
                o0.z = fmaxf(v[2], 0.f); o0.w = fmaxf(v[3], 0.f);
                o1.x = fmaxf(v[4], 0.f); o1.y = fmaxf(v[5], 0.f);
                o1.z = fmaxf(v[6], 0.f); o1.w = fmaxf(v[7], 0.f);
                Op[0] = o0; Op[1] = o1;
            } else {
                float m = v[0];
                #pragma unroll
                for (int i = 1; i < 8; ++i) m = fmaxf(m, v[i]);
                #pragma unroll
                for (int off = 4; off > 0; off >>= 1) m = fmaxf(m, __shfl_xor(m, off, 8));
                float e[8], s = 0.f;
                #pragma unroll
                for (int i = 0; i < 8; ++i) { e[i] = __expf(v[i] - m); s += e[i]; }
                #pragma unroll
                for (int off = 4; off > 0; off >>= 1) s += __shfl_xor(s, off, 8);
                float inv = 1.0f / s;
                float4 o0, o1;
                o0.x = e[0] * inv; o0.y = e[1] * inv; o0.z = e[2] * inv; o0.w = e[3] * inv;
                o1.x = e[4] * inv; o1.y = e[5] * inv; o1.z = e[6] * inv; o1.w = e[7] * inv;
                Op[0] = o0; Op[1] = o1;
            }
        }
    }
}

// ---------------------------------------------------------------------------
// The fused 3-layer cooperative kernel. 196 blocks x 512 threads, 1 block/CU
// (LDS 148KB). S never touches HBM: GEMM writes it to LDS, agg of the SAME
// block's nodes consumes it after a grid sync (Z must be globally complete).
// Layer 1 (128 cols) runs as two 64-col halves to fit S in LDS.
// ---------------------------------------------------------------------------
__global__ __launch_bounds__(512, 2) void fused3(
        const float* __restrict__ X,
        const ushort_t* __restrict__ P1sH, const ushort_t* __restrict__ P1sL,
        const ushort_t* __restrict__ P1nH, const ushort_t* __restrict__ P1nL,
        const float* __restrict__ b1,
        const ushort_t* __restrict__ P2sH, const ushort_t* __restrict__ P2sL,
        const ushort_t* __restrict__ P2nH, const ushort_t* __restrict__ P2nL,
        const float* __restrict__ b2,
        const ushort_t* __restrict__ P3sH, const ushort_t* __restrict__ P3sL,
        const ushort_t* __restrict__ P3nH, const ushort_t* __restrict__ P3nL,
        const float* __restrict__ b3,
        const int* __restrict__ row_ptr, const int* __restrict__ edge_src,
        const float* __restrict__ invd,
        ushort_t* __restrict__ Z0, ushort_t* __restrict__ Z1,
        float* __restrict__ H1, float* __restrict__ H2,
        float* __restrict__ out, int N) {
    __shared__ float Sl[NPB * 64];       // 128 KB: self-term, block-local
    __shared__ float bufZ[8 * 640];      // 20 KB: per-wave Z transpose buffers
    cg::grid_group grid = cg::this_grid();
    int tid = threadIdx.x;
    int nodeBase = blockIdx.x * NPB;

    // ---- Layer 1 (128 -> 128, relu), half 0: cols 0..63 ----
    gemm_phase<128, 8>(X, P1sH, P1sL, P1nH, P1nL, b1, 0, 0, Sl, Z0, bufZ, nodeBase, N, tid);
    grid.sync();                                     // Z0 complete grid-wide
    agg_phase<0>(Sl, Z0, row_ptr, edge_src, invd, H1, 128, 0, nodeBase, N, tid);
    __syncthreads();                                 // Sl reuse is block-local

    // ---- Layer 1, half 1: cols 64..127 ----
    gemm_phase<128, 8>(X, P1sH, P1sL, P1nH, P1nL, b1, 64, 4, Sl, Z1, bufZ, nodeBase, N, tid);
    grid.sync();                                     // Z1 complete
    agg_phase<0>(Sl, Z1, row_ptr, edge_src, invd, H1, 128, 64, nodeBase, N, tid);
    grid.sync();                                     // H1 visibility (own rows)

    // ---- Layer 2 (128 -> 64, relu) ----
    gemm_phase<128, 4>(H1, P2sH, P2sL, P2nH, P2nL, b2, 0, 0, Sl, Z0, bufZ, nodeBase, N, tid);
    grid.sync();
    agg_phase<0>(Sl, Z0, row_ptr, edge_src, invd, H2, 64, 0, nodeBase, N, tid);
    grid.sync();

    // ---- Layer 3 (64 -> 64, softmax) ----
    gemm_phase<64, 4>(H2, P3sH, P3sL, P3nH, P3nL, b3, 0, 0, Sl, Z1, bufZ, nodeBase, N, tid);
    grid.sync();
    agg_phase<1>(Sl, Z1, row_ptr, edge_src, invd, out, 64, 0, nodeBase, N, tid);
}

// ---------------------------------------------------------------------------
extern "C" void kernel_launch(void* const* d_in, const int* in_sizes, int n_in,
                              void* d_out, int out_size, void* d_ws, size_t ws_size,
                              hipStream_t stream) {
    const float* in_feat = (const float*)d_in[0];
    const int*   src     = (const int*)d_in[1];
    const int*   dst     = (const int*)d_in[2];
    const float* w1s = (const float*)d_in[3];
    const float* w1n = (const float*)d_in[4];
    const float* b1  = (const float*)d_in[5];
    const float* w2s = (const float*)d_in[6];
    const float* w2n = (const float*)d_in[7];
    const float* b2  = (const float*)d_in[8];
    const float* w3s = (const float*)d_in[9];
    const float* w3n = (const float*)d_in[10];
    const float* b3  = (const float*)d_in[11];

    const int N = N_NODES;
    const int E = in_sizes[1];

    char* p = (char*)d_ws;
    auto carve = [&](size_t bytes) -> char* {
        char* q = p;
        p += (bytes + 511) & ~(size_t)511;
        return q;
    };
    float*    H1       = (float*)   carve((size_t)N * 128 * sizeof(float));
    float*    H2       = (float*)   carve((size_t)N * 64 * sizeof(float));
    ushort_t* Z0       = (ushort_t*)carve((size_t)N * 64 * sizeof(ushort_t));
    ushort_t* Z1       = (ushort_t*)carve((size_t)N * 64 * sizeof(ushort_t));
    int*      edge_src = (int*)     carve((size_t)E * sizeof(int));
    int*      row_ptr  = (int*)     carve((size_t)(N + 1) * sizeof(int));
    int*      cursor   = (int*)     carve((size_t)N * sizeof(int));
    int*      deg      = (int*)     carve((size_t)N * sizeof(int));
    float*    invd     = (float*)   carve((size_t)N * sizeof(float));
    int*      partials = (int*)     carve(256 * sizeof(int));
    int*      gcur     = (int*)     carve(MAXBUCK * sizeof(int));
    // staging pairs alias H1 (H1 is only written after scatter completes)
    long long* staged  = (long long*)H1;
    // packed weights (hi/lo per matrix)
    ushort_t* P1sH = (ushort_t*)carve(128 * 128 * 2); ushort_t* P1sL = (ushort_t*)carve(128 * 128 * 2);
    ushort_t* P1nH = (ushort_t*)carve(128 * 128 * 2); ushort_t* P1nL = (ushort_t*)carve(128 * 128 * 2);
    ushort_t* P2sH = (ushort_t*)carve(128 * 64 * 2);  ushort_t* P2sL = (ushort_t*)carve(128 * 64 * 2);
    ushort_t* P2nH = (ushort_t*)carve(128 * 64 * 2);  ushort_t* P2nL = (ushort_t*)carve(128 * 64 * 2);
    ushort_t* P3sH = (ushort_t*)carve(64 * 64 * 2);   ushort_t* P3sL = (ushort_t*)carve(64 * 64 * 2);
    ushort_t* P3nH = (ushort_t*)carve(64 * 64 * 2);   ushort_t* P3nL = (ushort_t*)carve(64 * 64 * 2);

    // ---- CSR build + weight packing (pack fused into hist launch) ----
    (void)hipMemsetAsync(deg, 0, (size_t)N * sizeof(int), stream);
    pack_hist<<<28 + (E + 255) / 256, 256, 0, stream>>>(
        w1s, w1n, w2s, w2n, w3s, w3n,
        P1sH, P1sL, P1nH, P1nL,
        P2sH, P2sL, P2nH, P2nL,
        P3sH, P3sL, P3nH, P3nL,
        dst, deg, E);
    const int NB = (N + 1023) / 1024;   // 98 segments
    scan_partial_sums<<<NB, 256, 0, stream>>>(deg, partials, N);
    scan_partials<<<1, 256, 0, stream>>>(partials, NB, row_ptr, N);
    scan_emit<<<NB, 256, 0, stream>>>(deg, partials, row_ptr, cursor, invd, gcur, N);
    const int NBUCK = (N + 255) >> 8;          // 391 buckets of 256 nodes
    const int BINB  = 256;
    const int CHUNK = (E + BINB - 1) / BINB;
    bin_pairs<<<BINB, 256, 0, stream>>>(src, dst, gcur, staged, E, NBUCK, CHUNK);
    scatter_bucket<<<NBUCK, 256, 0, stream>>>(staged, row_ptr, cursor, edge_src, N);

    // ---- fused 3-layer cooperative kernel ----
    int Nv = N;
    float* outp = (float*)d_out;
    void* kargs[] = {
        (void*)&in_feat,
        (void*)&P1sH, (void*)&P1sL, (void*)&P1nH, (void*)&P1nL, (void*)&b1,
        (void*)&P2sH, (void*)&P2sL, (void*)&P2nH, (void*)&P2nL, (void*)&b2,
        (void*)&P3sH, (void*)&P3sL, (void*)&P3nH, (void*)&P3nL, (void*)&b3,
        (void*)&row_ptr, (void*)&edge_src, (void*)&invd,
        (void*)&Z0, (void*)&Z1, (void*)&H1, (void*)&H2,
        (void*)&outp, (void*)&Nv
    };
    (void)hipLaunchCooperativeKernel((void*)fused3, dim3(FGRID), dim3(512),
                                     kargs, 0, stream);
}

// Round 5
// 478.175 us; speedup vs baseline: 1.4647x; 1.4647x over previous
//
#include <hip/hip_runtime.h>
#include <hip/hip_bf16.h>

#define N_NODES 100000

typedef unsigned short ushort_t;
typedef __attribute__((ext_vector_type(8))) short short8;
typedef __attribute__((ext_vector_type(4))) float f32x4;

// ---------------------------------------------------------------------------
// helpers
// ---------------------------------------------------------------------------
static __device__ __forceinline__ ushort_t f2bf(float f) {
    unsigned u = __float_as_uint(f);
    unsigned r = u + 0x7FFFu + ((u >> 16) & 1u);   // round-to-nearest-even
    return (ushort_t)(r >> 16);
}
static __device__ __forceinline__ float bf2f(ushort_t h) {
    return __uint_as_float(((unsigned)h) << 16);
}

// split 8 contiguous fp32 into hi/lo bf16 fragments
static __device__ __forceinline__ void split8(const float* __restrict__ xp,
                                              short8& hi, short8& lo) {
    float4 x0 = *(const float4*)xp;
    float4 x1 = *(const float4*)(xp + 4);
    float xs[8] = {x0.x, x0.y, x0.z, x0.w, x1.x, x1.y, x1.z, x1.w};
    #pragma unroll
    for (int j = 0; j < 8; ++j) {
        ushort_t h = f2bf(xs[j]);
        hi[j] = (short)h;
        lo[j] = (short)f2bf(xs[j] - bf2f(h));
    }
}

// unpack-accumulate one u32 (2 bf16) into two fp32 accumulators
static __device__ __forceinline__ void acc_u32(unsigned w, float& a0, float& a1) {
    a0 += __uint_as_float(w << 16);
    a1 += __uint_as_float(w & 0xFFFF0000u);
}

// ---------------------------------------------------------------------------
// CSR build: histogram -> 3-phase scan -> bucket-binning -> exclusive scatter
// ---------------------------------------------------------------------------

// phase 1: per-block (1024-elem segment) total
__global__ __launch_bounds__(256) void scan_partial_sums(const int* __restrict__ deg,
                                                         int* __restrict__ partials, int N) {
    __shared__ int wsums[4];
    int tid = threadIdx.x, lane = tid & 63, wv = tid >> 6;
    int i0 = blockIdx.x * 1024 + tid * 4;
    int s = 0;
    #pragma unroll
    for (int j = 0; j < 4; ++j) {
        int i = i0 + j;
        if (i < N) s += deg[i];
    }
    #pragma unroll
    for (int off = 32; off > 0; off >>= 1) s += __shfl_xor(s, off, 64);
    if (lane == 0) wsums[wv] = s;
    __syncthreads();
    if (tid == 0)
        partials[blockIdx.x] = wsums[0] + wsums[1] + wsums[2] + wsums[3];
}

// phase 2: single block scans NB (<=256) partials -> exclusive, writes row_ptr[N]
__global__ __launch_bounds__(256) void scan_partials(int* __restrict__ partials, int NB,
                                                     int* __restrict__ row_ptr, int N) {
    __shared__ int wsums[4];
    int tid = threadIdx.x, lane = tid & 63, wv = tid >> 6;
    int v = (tid < NB) ? partials[tid] : 0;
    int x = v;
    #pragma unroll
    for (int off = 1; off < 64; off <<= 1) {
        int y = __shfl_up(x, off, 64);
        if (lane >= off) x += y;
    }
    if (lane == 63) wsums[wv] = x;
    __syncthreads();
    int woff = 0;
    for (int w = 0; w < wv; ++w) woff += wsums[w];
    int incl = x + woff;
    if (tid < NB) partials[tid] = incl - v;          // exclusive
    if (tid == NB - 1) row_ptr[N] = incl;            // grand total
}

// phase 3: emit row_ptr/cursor/invd; also init per-bucket cursor gcur
__global__ __launch_bounds__(256) void scan_emit(const int* __restrict__ deg,
                                                 const int* __restrict__ partials,
                                                 int* __restrict__ row_ptr,
                                                 int* __restrict__ cursor,
                                                 float* __restrict__ inv_deg,
                                                 int* __restrict__ gcur, int N) {
    __shared__ int wsums[4];
    int tid = threadIdx.x, lane = tid & 63, wv = tid >> 6;
    int i0 = blockIdx.x * 1024 + tid * 4;
    int d[4];
    #pragma unroll
    for (int j = 0; j < 4; ++j) {
        int i = i0 + j;
        d[j] = (i < N) ? deg[i] : 0;
    }
    int s = d[0] + d[1] + d[2] + d[3];
    int x = s;
    #pragma unroll
    for (int off = 1; off < 64; off <<= 1) {
        int y = __shfl_up(x, off, 64);
        if (lane >= off) x += y;
    }
    if (lane == 63) wsums[wv] = x;
    __syncthreads();
    int woff = 0;
    for (int w = 0; w < wv; ++w) woff += wsums[w];
    int run = partials[blockIdx.x] + woff + x - s;   // exclusive prefix of elem i0
    #pragma unroll
    for (int j = 0; j < 4; ++j) {
        int i = i0 + j;
        if (i < N) {
            row_ptr[i] = run;
            cursor[i]  = run;
            inv_deg[i] = 1.0f / (float)(d[j] > 0 ? d[j] : 1);
            if ((i & 255) == 0) gcur[i >> 8] = run;   // bucket staging base
            run += d[j];
        }
    }
}

// ---------------------------------------------------------------------------
// Weight pre-pack (6 matrices) MERGED with degree histogram
// ---------------------------------------------------------------------------
__global__ __launch_bounds__(256) void pack_hist(
        const float* __restrict__ W0, const float* __restrict__ W1,
        const float* __restrict__ W2, const float* __restrict__ W3,
        const float* __restrict__ W4, const float* __restrict__ W5,
        ushort_t* H0, ushort_t* L0, ushort_t* H1, ushort_t* L1,
        ushort_t* H2, ushort_t* L2, ushort_t* H3, ushort_t* L3,
        ushort_t* H4, ushort_t* L4, ushort_t* H5, ushort_t* L5,
        const int* __restrict__ dst, int* __restrict__ deg, int E) {
    int b = blockIdx.x;
    if (b >= 28) {
        int e = (b - 28) * 256 + threadIdx.x;
        if (e < E) atomicAdd(&deg[__builtin_nontemporal_load(&dst[e])], 1);
        return;
    }
    const float* W; ushort_t* Hi; ushort_t* Lo; int K, NS, base;
    if (b < 8)       { W = W0; Hi = H0; Lo = L0; K = 128; NS = 128; base = 0;  }
    else if (b < 16) { W = W1; Hi = H1; Lo = L1; K = 128; NS = 128; base = 8;  }
    else if (b < 20) { W = W2; Hi = H2; Lo = L2; K = 128; NS = 64;  base = 16; }
    else if (b < 24) { W = W3; Hi = H3; Lo = L3; K = 128; NS = 64;  base = 20; }
    else if (b < 26) { W = W4; Hi = H4; Lo = L4; K = 64;  NS = 64;  base = 24; }
    else             { W = W5; Hi = H5; Lo = L5; K = 64;  NS = 64;  base = 26; }
    int tid = (b - base) * 256 + threadIdx.x;
    if (tid >= (K * NS) / 8) return;
    int l  = tid & 63;
    int fl = tid >> 6;
    int NT = NS / 16;
    int t = fl % NT, s = fl / NT;
    ushort_t hs[8], ls[8];
    #pragma unroll
    for (int j = 0; j < 8; ++j) {
        int k = s * 32 + (l >> 4) * 8 + j;
        int n = t * 16 + (l & 15);
        float w = W[(size_t)k * NS + n];
        ushort_t h = f2bf(w);
        hs[j] = h;
        ls[j] = f2bf(w - bf2f(h));
    }
    #pragma unroll
    for (int j = 0; j < 8; ++j) {
        Hi[(size_t)tid * 8 + j] = hs[j];
        Lo[(size_t)tid * 8 + j] = ls[j];
    }
}

// ---------------------------------------------------------------------------
// MFMA dual GEMM body (split-bf16, fp32-grade) with LDS-transposed epilogue.
// Identical math/layout to the verified R0-R3 kernel; shared buffers passed in
// so the body can be embedded in heterogeneous launches (bin/scatter overlap).
// ---------------------------------------------------------------------------
template <int K, int NS>
static __device__ __forceinline__ void gemm_body(
        int gblk,
        const float* __restrict__ X,
        const ushort_t* __restrict__ BsHi, const ushort_t* __restrict__ BsLo,
        const ushort_t* __restrict__ BnHi, const ushort_t* __restrict__ BnLo,
        const float* __restrict__ bias,
        float* __restrict__ S, ushort_t* __restrict__ Zb, int M,
        float* __restrict__ ldsS, float* __restrict__ ldsZ) {
    constexpr int KS = K / 32;      // mfma k-steps
    constexpr int NT = NS / 16;     // n-tiles
    int tid = threadIdx.x;
    int lane = tid & 63, w = tid >> 6;
    int baseM = gblk * 128 + w * 32;
    int rIn = lane & 15, q = lane >> 4;
    float* bufS = ldsS + w * 640;   // per-wave private 32x20 transpose buffers
    float* bufZ = ldsZ + w * 640;

    // ---- load + split all A fragments for this wave's 32 rows ----
    short8 Ahi[KS][2], Alo[KS][2];
    #pragma unroll
    for (int s = 0; s < KS; ++s) {
        #pragma unroll
        for (int mt = 0; mt < 2; ++mt) {
            int gm = baseM + mt * 16 + rIn;
            if (gm < M) {
                split8(&X[(size_t)gm * K + s * 32 + q * 8], Ahi[s][mt], Alo[s][mt]);
            } else {
                #pragma unroll
                for (int j = 0; j < 8; ++j) { Ahi[s][mt][j] = 0; Alo[s][mt][j] = 0; }
            }
        }
    }

    // ---- loop n-tiles; stream B frags from L2; 12 MFMA per (s,t) ----
    for (int t = 0; t < NT; ++t) {
        f32x4 aS0 = {0.f, 0.f, 0.f, 0.f}, aS1 = {0.f, 0.f, 0.f, 0.f};
        f32x4 aZ0 = {0.f, 0.f, 0.f, 0.f}, aZ1 = {0.f, 0.f, 0.f, 0.f};
        #pragma unroll
        for (int s = 0; s < KS; ++s) {
            size_t fo = ((size_t)(s * NT + t) * 64 + lane) * 8;
            short8 bsh = *(const short8*)&BsHi[fo];
            short8 bsl = *(const short8*)&BsLo[fo];
            short8 bnh = *(const short8*)&BnHi[fo];
            short8 bnl = *(const short8*)&BnLo[fo];
            aS0 = __builtin_amdgcn_mfma_f32_16x16x32_bf16(Ahi[s][0], bsh, aS0, 0, 0, 0);
            aS0 = __builtin_amdgcn_mfma_f32_16x16x32_bf16(Alo[s][0], bsh, aS0, 0, 0, 0);
            aS0 = __builtin_amdgcn_mfma_f32_16x16x32_bf16(Ahi[s][0], bsl, aS0, 0, 0, 0);
            aS1 = __builtin_amdgcn_mfma_f32_16x16x32_bf16(Ahi[s][1], bsh, aS1, 0, 0, 0);
            aS1 = __builtin_amdgcn_mfma_f32_16x16x32_bf16(Alo[s][1], bsh, aS1, 0, 0, 0);
            aS1 = __builtin_amdgcn_mfma_f32_16x16x32_bf16(Ahi[s][1], bsl, aS1, 0, 0, 0);
            aZ0 = __builtin_amdgcn_mfma_f32_16x16x32_bf16(Ahi[s][0], bnh, aZ0, 0, 0, 0);
            aZ0 = __builtin_amdgcn_mfma_f32_16x16x32_bf16(Alo[s][0], bnh, aZ0, 0, 0, 0);
            aZ0 = __builtin_amdgcn_mfma_f32_16x16x32_bf16(Ahi[s][0], bnl, aZ0, 0, 0, 0);
            aZ1 = __builtin_amdgcn_mfma_f32_16x16x32_bf16(Ahi[s][1], bnh, aZ1, 0, 0, 0);
            aZ1 = __builtin_amdgcn_mfma_f32_16x16x32_bf16(Alo[s][1], bnh, aZ1, 0, 0, 0);
            aZ1 = __builtin_amdgcn_mfma_f32_16x16x32_bf16(Ahi[s][1], bnl, aZ1, 0, 0, 0);
        }
        // ---- epilogue: C layout (col=rIn, row=q*4+r) -> LDS -> float4 stores
        #pragma unroll
        for (int r = 0; r < 4; ++r) {
            bufS[(q * 4 + r) * 20 + rIn]        = aS0[r];
            bufS[(16 + q * 4 + r) * 20 + rIn]   = aS1[r];
            bufZ[(q * 4 + r) * 20 + rIn]        = aZ0[r];
            bufZ[(16 + q * 4 + r) * 20 + rIn]   = aZ1[r];
        }
        int row = lane >> 2;            // 0..15
        int cq  = lane & 3;
        int col = t * 16 + cq * 4;
        float4 bv = *(const float4*)&bias[col];
        #pragma unroll
        for (int half = 0; half < 2; ++half) {
            int gm = baseM + half * 16 + row;
            float4 v = *(float4*)&bufS[(half * 16 + row) * 20 + cq * 4];
            float4 z = *(float4*)&bufZ[(half * 16 + row) * 20 + cq * 4];
            if (gm < M) {
                float4 o;
                o.x = v.x + bv.x; o.y = v.y + bv.y;
                o.z = v.z + bv.z; o.w = v.w + bv.w;
                *(float4*)&S[(size_t)gm * NS + col] = o;
                uint2 o2;
                o2.x = (unsigned)f2bf(z.x) | ((unsigned)f2bf(z.y) << 16);
                o2.y = (unsigned)f2bf(z.z) | ((unsigned)f2bf(z.w) << 16);
                *(uint2*)&Zb[(size_t)gm * NS + col] = o2;
            }
        }
    }
}

// plain GEMM kernel (layers 2 and 3)
template <int K, int NS>
__global__ __launch_bounds__(256) void mfma_gemm(const float* __restrict__ X,
                                                 const ushort_t* __restrict__ BsHi,
                                                 const ushort_t* __restrict__ BsLo,
                                                 const ushort_t* __restrict__ BnHi,
                                                 const ushort_t* __restrict__ BnLo,
                                                 const float* __restrict__ bias,
                                                 float* __restrict__ S,
                                                 ushort_t* __restrict__ Zb,
                                                 int M) {
    __shared__ float ldsS[4 * 640];
    __shared__ float ldsZ[4 * 640];
    gemm_body<K, NS>(blockIdx.x, X, BsHi, BsLo, BnHi, BnLo, bias, S, Zb, M, ldsS, ldsZ);
}

// ---------------------------------------------------------------------------
// Heterogeneous launch A: blocks [0,256) bin edge pairs into bucket staging;
// blocks [256, 256+GH) run GEMM1 row-blocks gblk = b-256 (0..GH-1).
// bin is memory/atomic-bound, GEMM is MFMA-bound -> they overlap on the CUs.
// ---------------------------------------------------------------------------
#define MAXBUCK 512
__global__ __launch_bounds__(256) void bin_gemm1(
        const int* __restrict__ src, const int* __restrict__ dst,
        int* __restrict__ gcur, long long* __restrict__ staged,
        int E, int NBUCK, int C,
        const float* __restrict__ X,
        const ushort_t* __restrict__ BsHi, const ushort_t* __restrict__ BsLo,
        const ushort_t* __restrict__ BnHi, const ushort_t* __restrict__ BnLo,
        const float* __restrict__ bias,
        float* __restrict__ S, ushort_t* __restrict__ Zb, int M) {
    __shared__ float ldsS[4 * 640];
    __shared__ float ldsZ[4 * 640];
    __shared__ int cnt[MAXBUCK];
    int b = blockIdx.x;
    if (b >= 256) {
        gemm_body<128, 128>(b - 256, X, BsHi, BsLo, BnHi, BnLo, bias, S, Zb, M, ldsS, ldsZ);
        return;
    }
    int tid = threadIdx.x;
    int e0 = b * C;
    int e1 = min(e0 + C, E);
    for (int k = tid; k < NBUCK; k += 256) cnt[k] = 0;
    __syncthreads();
    for (int e = e0 + tid; e < e1; e += 256) {
        int d = __builtin_nontemporal_load(&dst[e]);
        atomicAdd(&cnt[d >> 8], 1);
    }
    __syncthreads();
    for (int k = tid; k < NBUCK; k += 256) {
        int c = cnt[k];
        cnt[k] = (c > 0) ? atomicAdd(&gcur[k], c) : 0;   // LDS cursor = global pos
    }
    __syncthreads();
    for (int e = e0 + tid; e < e1; e += 256) {
        int d = __builtin_nontemporal_load(&dst[e]);
        int s = __builtin_nontemporal_load(&src[e]);
        int p = atomicAdd(&cnt[d >> 8], 1);
        staged[p] = ((long long)d << 32) | (unsigned)s;   // hi=dst, lo=src
    }
}

// ---------------------------------------------------------------------------
// Heterogeneous launch B: blocks [0, NBUCK) scatter staged pairs into CSR
// order; blocks [NBUCK, NBUCK+GB-GH) run GEMM1 row-blocks gblk = GH + b-NBUCK.
// ---------------------------------------------------------------------------
__global__ __launch_bounds__(256) void scatter_gemm1(
        const long long* __restrict__ staged,
        const int* __restrict__ row_ptr,
        int* __restrict__ cursor, int* __restrict__ edge_src, int N,
        int NBUCK, int GH,
        const float* __restrict__ X,
        const ushort_t* __restrict__ BsHi, const ushort_t* __restrict__ BsLo,
        const ushort_t* __restrict__ BnHi, const ushort_t* __restrict__ BnLo,
        const float* __restrict__ bias,
        float* __restrict__ S, ushort_t* __restrict__ Zb, int M) {
    __shared__ float ldsS[4 * 640];
    __shared__ float ldsZ[4 * 640];
    int b = blockIdx.x;
    if (b >= NBUCK) {
        gemm_body<128, 128>(GH + (b - NBUCK), X, BsHi, BsLo, BnHi, BnLo, bias, S, Zb, M,
                            ldsS, ldsZ);
        return;
    }
    int lo = b << 8;
    int hiN = min((b + 1) << 8, N);
    int gstart = row_ptr[lo];
    int gend   = row_ptr[hiN];
    for (int p = gstart + threadIdx.x; p < gend; p += 256) {
        long long pr = __builtin_nontemporal_load(&staged[p]);
        int d = (int)(pr >> 32);
        int s = (int)(pr & 0xFFFFFFFFll);
        int pos = atomicAdd(&cursor[d], 1);
        edge_src[pos] = s;
    }
}

// ---------------------------------------------------------------------------
// Aggregate with bf16 Z: out[n,f] = act( S[n,f] + inv_deg[n]*sum Z[src,f] )
// G = D/8 lanes per node (16 for D=128, 8 for D=64); every lane gathers 16B
// (uint4). Edge indices loaded cooperatively + shfl broadcast. S/invd hoisted.
// ACT: 0 = relu, 1 = softmax across the 8-lane group (D=64 only)
// (Verified at the random-gather pattern floor in R0-R3: ~3.8 TB/s, ~205 MB.)
// ---------------------------------------------------------------------------
template <int D, int ACT>
__global__ __launch_bounds__(256) void agg_kernel(const float* __restrict__ S,
                                                  const ushort_t* __restrict__ Zb,
                                                  const int* __restrict__ row_ptr,
                                                  const int* __restrict__ edge_src,
                                                  const float* __restrict__ inv_deg,
                                                  float* __restrict__ out, int N) {
    constexpr int G  = D / 8;          // lanes per node: 16 (D=128) / 8 (D=64)
    constexpr int PF = 8;              // floats per lane (both widths)
    constexpr int NG = 256 / G;        // nodes per block: 16 / 32
    constexpr int U  = G;              // edges per batch = lanes per group
    int tid = threadIdx.x;
    int g = tid / G, fl = tid % G;
    int n = blockIdx.x * NG + g;
    if (n >= N) return;
    int beg = row_ptr[n], end = row_ptr[n + 1];
    float id = inv_deg[n];

    // hoisted stream loads (overlap with gathers)
    const f32x4* Sp = (const f32x4*)(S + (size_t)n * D) + fl * 2;
    f32x4 s40 = __builtin_nontemporal_load(Sp);
    f32x4 s41 = __builtin_nontemporal_load(Sp + 1);

    float acc[2][PF];
    #pragma unroll
    for (int i = 0; i < PF; ++i) { acc[0][i] = 0.f; acc[1][i] = 0.f; }

    const char* zlane = (const char*)Zb + fl * 16;   // 16B per lane within row

    for (int j = beg; j < end; j += U) {
        int je = j + fl;
        int myS = (je < end) ? __builtin_nontemporal_load(&edge_src[je]) : -1;
        uint4 u[U];
        #pragma unroll
        for (int k = 0; k < U; ++k) {
            int s = __shfl(myS, k, U);   // broadcast within the G-lane group
            u[k] = make_uint4(0u, 0u, 0u, 0u);
            if (s >= 0)
                u[k] = *(const uint4*)(zlane + ((size_t)((unsigned)s) * (D * 2)));
        }
        #pragma unroll
        for (int k = 0; k < U; ++k) {
            acc_u32(u[k].x, acc[k & 1][0], acc[k & 1][1]);
            acc_u32(u[k].y, acc[k & 1][2], acc[k & 1][3]);
            acc_u32(u[k].z, acc[k & 1][4], acc[k & 1][5]);
            acc_u32(u[k].w, acc[k & 1][6], acc[k & 1][7]);
        }
    }

    float v[PF];
    #pragma unroll
    for (int i = 0; i < 4; ++i) {
        v[i]     = s40[i] + id * (acc[0][i]     + acc[1][i]);
        v[4 + i] = s41[i] + id * (acc[0][4 + i] + acc[1][4 + i]);
    }

    float4* Op = (float4*)(out + (size_t)n * D) + fl * 2;
    if constexpr (ACT == 0) {
        float4 o0, o1;
        o0.x = fmaxf(v[0], 0.f); o0.y = fmaxf(v[1], 0.f);
        o0.z = fmaxf(v[2], 0.f); o0.w = fmaxf(v[3], 0.f);
        o1.x = fmaxf(v[4], 0.f); o1.y = fmaxf(v[5], 0.f);
        o1.z = fmaxf(v[6], 0.f); o1.w = fmaxf(v[7], 0.f);
        Op[0] = o0; Op[1] = o1;
    } else {
        // softmax across 8 lanes x 8 vals (D == 64)
        float m = v[0];
        #pragma unroll
        for (int i = 1; i < 8; ++i) m = fmaxf(m, v[i]);
        #pragma unroll
        for (int off = 4; off > 0; off >>= 1) m = fmaxf(m, __shfl_xor(m, off, 8));
        float e[8], s = 0.f;
        #pragma unroll
        for (int i = 0; i < 8; ++i) { e[i] = __expf(v[i] - m); s += e[i]; }
        #pragma unroll
        for (int off = 4; off > 0; off >>= 1) s += __shfl_xor(s, off, 8);
        float inv = 1.0f / s;
        float4 o0, o1;
        o0.x = e[0] * inv; o0.y = e[1] * inv; o0.z = e[2] * inv; o0.w = e[3] * inv;
        o1.x = e[4] * inv; o1.y = e[5] * inv; o1.z = e[6] * inv; o1.w = e[7] * inv;
        Op[0] = o0; Op[1] = o1;
    }
}

// ---------------------------------------------------------------------------
extern "C" void kernel_launch(void* const* d_in, const int* in_sizes, int n_in,
                              void* d_out, int out_size, void* d_ws, size_t ws_size,
                              hipStream_t stream) {
    const float* in_feat = (const float*)d_in[0];
    const int*   src     = (const int*)d_in[1];
    const int*   dst     = (const int*)d_in[2];
    const float* w1s = (const float*)d_in[3];
    const float* w1n = (const float*)d_in[4];
    const float* b1  = (const float*)d_in[5];
    const float* w2s = (const float*)d_in[6];
    const float* w2n = (const float*)d_in[7];
    const float* b2  = (const float*)d_in[8];
    const float* w3s = (const float*)d_in[9];
    const float* w3n = (const float*)d_in[10];
    const float* b3  = (const float*)d_in[11];

    const int N = N_NODES;
    const int E = in_sizes[1];

    char* p = (char*)d_ws;
    auto carve = [&](size_t bytes) -> char* {
        char* q = p;
        p += (bytes + 511) & ~(size_t)511;
        return q;
    };
    float*    S        = (float*)   carve((size_t)N * 128 * sizeof(float));
    ushort_t* Zb       = (ushort_t*)carve((size_t)N * 128 * sizeof(ushort_t));
    float*    H        = (float*)   carve((size_t)N * 128 * sizeof(float));
    int*      edge_src = (int*)     carve((size_t)E * sizeof(int));
    int*      row_ptr  = (int*)     carve((size_t)(N + 1) * sizeof(int));
    int*      cursor   = (int*)     carve((size_t)N * sizeof(int));
    int*      deg      = (int*)     carve((size_t)N * sizeof(int));
    float*    invd     = (float*)   carve((size_t)N * sizeof(float));
    int*      partials = (int*)     carve(256 * sizeof(int));
    int*      gcur     = (int*)     carve(MAXBUCK * sizeof(int));
    // staging pairs alias H (H is only written after scatter completes)
    long long* staged  = (long long*)H;
    // packed weights (hi/lo per matrix)
    ushort_t* P1sH = (ushort_t*)carve(128 * 128 * 2); ushort_t* P1sL = (ushort_t*)carve(128 * 128 * 2);
    ushort_t* P1nH = (ushort_t*)carve(128 * 128 * 2); ushort_t* P1nL = (ushort_t*)carve(128 * 128 * 2);
    ushort_t* P2sH = (ushort_t*)carve(128 * 64 * 2);  ushort_t* P2sL = (ushort_t*)carve(128 * 64 * 2);
    ushort_t* P2nH = (ushort_t*)carve(128 * 64 * 2);  ushort_t* P2nL = (ushort_t*)carve(128 * 64 * 2);
    ushort_t* P3sH = (ushort_t*)carve(64 * 64 * 2);   ushort_t* P3sL = (ushort_t*)carve(64 * 64 * 2);
    ushort_t* P3nH = (ushort_t*)carve(64 * 64 * 2);   ushort_t* P3nL = (ushort_t*)carve(64 * 64 * 2);

    // ---- CSR build + weight packing (pack fused into hist launch) ----
    (void)hipMemsetAsync(deg, 0, (size_t)N * sizeof(int), stream);
    pack_hist<<<28 + (E + 255) / 256, 256, 0, stream>>>(
        w1s, w1n, w2s, w2n, w3s, w3n,
        P1sH, P1sL, P1nH, P1nL,
        P2sH, P2sL, P2nH, P2nL,
        P3sH, P3sL, P3nH, P3nL,
        dst, deg, E);
    const int NB = (N + 1023) / 1024;   // 98 segments
    scan_partial_sums<<<NB, 256, 0, stream>>>(deg, partials, N);
    scan_partials<<<1, 256, 0, stream>>>(partials, NB, row_ptr, N);
    scan_emit<<<NB, 256, 0, stream>>>(deg, partials, row_ptr, cursor, invd, gcur, N);

    const int GB    = (N + 127) / 128;   // 782 GEMM row blocks
    const int GH    = GB / 2;            // 391: GEMM1 blocks in launch A
    const int NBUCK = (N + 255) >> 8;    // 391 buckets of 256 nodes
    const int BINB  = 256;
    const int CHUNK = (E + BINB - 1) / BINB;

    // ---- launch A: bin (256 blocks) + GEMM1 first half (GH blocks) ----
    bin_gemm1<<<256 + GH, 256, 0, stream>>>(
        src, dst, gcur, staged, E, NBUCK, CHUNK,
        in_feat, P1sH, P1sL, P1nH, P1nL, b1, S, Zb, N);

    // ---- launch B: scatter (NBUCK blocks) + GEMM1 second half ----
    scatter_gemm1<<<NBUCK + (GB - GH), 256, 0, stream>>>(
        staged, row_ptr, cursor, edge_src, N, NBUCK, GH,
        in_feat, P1sH, P1sL, P1nH, P1nL, b1, S, Zb, N);

    const int AB128 = (N + 15) / 16;    // agg blocks, D=128: 16 nodes each
    const int AB64  = (N + 31) / 32;    // agg blocks, D=64:  32 nodes each

    // ---- Layer 1 aggregate (GEMM1 done in launches A+B) ----
    agg_kernel<128, 0><<<AB128, 256, 0, stream>>>(S, Zb, row_ptr, edge_src, invd, H, N);

    // ---- Layer 2: 128 -> 64, relu ----
    mfma_gemm<128, 64><<<GB, 256, 0, stream>>>(H, P2sH, P2sL, P2nH, P2nL, b2, S, Zb, N);
    agg_kernel<64, 0><<<AB64, 256, 0, stream>>>(S, Zb, row_ptr, edge_src, invd, H, N);

    // ---- Layer 3: 64 -> 64, softmax ----
    mfma_gemm<64, 64><<<GB, 256, 0, stream>>>(H, P3sH, P3sL, P3nH, P3nL, b3, S, Zb, N);
    agg_kernel<64, 1><<<AB64, 256, 0, stream>>>(S, Zb, row_ptr, edge_src, invd,
                                                (float*)d_out, N);
}

// Round 6
// 463.791 us; speedup vs baseline: 1.5101x; 1.0310x over previous
//
#include <hip/hip_runtime.h>
#include <hip/hip_bf16.h>

#define N_NODES 100000

typedef unsigned short ushort_t;
typedef __attribute__((ext_vector_type(8))) short short8;
typedef __attribute__((ext_vector_type(4))) float f32x4;

// ---------------------------------------------------------------------------
// helpers
// ---------------------------------------------------------------------------
static __device__ __forceinline__ ushort_t f2bf(float f) {
    unsigned u = __float_as_uint(f);
    unsigned r = u + 0x7FFFu + ((u >> 16) & 1u);   // round-to-nearest-even
    return (ushort_t)(r >> 16);
}
static __device__ __forceinline__ float bf2f(ushort_t h) {
    return __uint_as_float(((unsigned)h) << 16);
}

// split 8 contiguous fp32 into hi/lo bf16 fragments
static __device__ __forceinline__ void split8(const float* __restrict__ xp,
                                              short8& hi, short8& lo) {
    float4 x0 = *(const float4*)xp;
    float4 x1 = *(const float4*)(xp + 4);
    float xs[8] = {x0.x, x0.y, x0.z, x0.w, x1.x, x1.y, x1.z, x1.w};
    #pragma unroll
    for (int j = 0; j < 8; ++j) {
        ushort_t h = f2bf(xs[j]);
        hi[j] = (short)h;
        lo[j] = (short)f2bf(xs[j] - bf2f(h));
    }
}

// unpack-accumulate one u32 (2 bf16) into two fp32 accumulators
static __device__ __forceinline__ void acc_u32(unsigned w, float& a0, float& a1) {
    a0 += __uint_as_float(w << 16);
    a1 += __uint_as_float(w & 0xFFFF0000u);
}

// ---------------------------------------------------------------------------
// CSR build: histogram -> 3-phase scan -> bucket-binning -> exclusive scatter
// ---------------------------------------------------------------------------

// phase 1: per-block (1024-elem segment) total
__global__ __launch_bounds__(256) void scan_partial_sums(const int* __restrict__ deg,
                                                         int* __restrict__ partials, int N) {
    __shared__ int wsums[4];
    int tid = threadIdx.x, lane = tid & 63, wv = tid >> 6;
    int i0 = blockIdx.x * 1024 + tid * 4;
    int s = 0;
    #pragma unroll
    for (int j = 0; j < 4; ++j) {
        int i = i0 + j;
        if (i < N) s += deg[i];
    }
    #pragma unroll
    for (int off = 32; off > 0; off >>= 1) s += __shfl_xor(s, off, 64);
    if (lane == 0) wsums[wv] = s;
    __syncthreads();
    if (tid == 0)
        partials[blockIdx.x] = wsums[0] + wsums[1] + wsums[2] + wsums[3];
}

// phase 2: single block scans NB (<=256) partials -> exclusive, writes row_ptr[N]
__global__ __launch_bounds__(256) void scan_partials(int* __restrict__ partials, int NB,
                                                     int* __restrict__ row_ptr, int N) {
    __shared__ int wsums[4];
    int tid = threadIdx.x, lane = tid & 63, wv = tid >> 6;
    int v = (tid < NB) ? partials[tid] : 0;
    int x = v;
    #pragma unroll
    for (int off = 1; off < 64; off <<= 1) {
        int y = __shfl_up(x, off, 64);
        if (lane >= off) x += y;
    }
    if (lane == 63) wsums[wv] = x;
    __syncthreads();
    int woff = 0;
    for (int w = 0; w < wv; ++w) woff += wsums[w];
    int incl = x + woff;
    if (tid < NB) partials[tid] = incl - v;          // exclusive
    if (tid == NB - 1) row_ptr[N] = incl;            // grand total
}

// phase 3: emit row_ptr/cursor/invd; also init per-bucket cursor gcur
__global__ __launch_bounds__(256) void scan_emit(const int* __restrict__ deg,
                                                 const int* __restrict__ partials,
                                                 int* __restrict__ row_ptr,
                                                 int* __restrict__ cursor,
                                                 float* __restrict__ inv_deg,
                                                 int* __restrict__ gcur, int N) {
    __shared__ int wsums[4];
    int tid = threadIdx.x, lane = tid & 63, wv = tid >> 6;
    int i0 = blockIdx.x * 1024 + tid * 4;
    int d[4];
    #pragma unroll
    for (int j = 0; j < 4; ++j) {
        int i = i0 + j;
        d[j] = (i < N) ? deg[i] : 0;
    }
    int s = d[0] + d[1] + d[2] + d[3];
    int x = s;
    #pragma unroll
    for (int off = 1; off < 64; off <<= 1) {
        int y = __shfl_up(x, off, 64);
        if (lane >= off) x += y;
    }
    if (lane == 63) wsums[wv] = x;
    __syncthreads();
    int woff = 0;
    for (int w = 0; w < wv; ++w) woff += wsums[w];
    int run = partials[blockIdx.x] + woff + x - s;   // exclusive prefix of elem i0
    #pragma unroll
    for (int j = 0; j < 4; ++j) {
        int i = i0 + j;
        if (i < N) {
            row_ptr[i] = run;
            cursor[i]  = run;
            inv_deg[i] = 1.0f / (float)(d[j] > 0 ? d[j] : 1);
            if ((i & 255) == 0) gcur[i >> 8] = run;   // bucket staging base
            run += d[j];
        }
    }
}

// Phase A: bin (src,dst) pairs into bucket-ordered staging (bucket = dst>>8).
#define MAXBUCK 512
__global__ __launch_bounds__(256) void bin_pairs(const int* __restrict__ src,
                                                 const int* __restrict__ dst,
                                                 int* __restrict__ gcur,
                                                 long long* __restrict__ staged,
                                                 int E, int NBUCK, int C) {
    __shared__ int cnt[MAXBUCK];
    int tid = threadIdx.x;
    int e0 = blockIdx.x * C;
    int e1 = min(e0 + C, E);
    for (int b = tid; b < NBUCK; b += 256) cnt[b] = 0;
    __syncthreads();
    for (int e = e0 + tid; e < e1; e += 256) {
        int d = __builtin_nontemporal_load(&dst[e]);
        atomicAdd(&cnt[d >> 8], 1);
    }
    __syncthreads();
    for (int b = tid; b < NBUCK; b += 256) {
        int c = cnt[b];
        cnt[b] = (c > 0) ? atomicAdd(&gcur[b], c) : 0;   // now LDS cursor = global pos
    }
    __syncthreads();
    for (int e = e0 + tid; e < e1; e += 256) {
        int d = __builtin_nontemporal_load(&dst[e]);
        int s = __builtin_nontemporal_load(&src[e]);
        int p = atomicAdd(&cnt[d >> 8], 1);
        staged[p] = ((long long)d << 32) | (unsigned)s;   // hi=dst, lo=src
    }
}

// Phase B: one block per bucket; scatter within a private ~16KB edge_src window
__global__ __launch_bounds__(256) void scatter_bucket(const long long* __restrict__ staged,
                                                      const int* __restrict__ row_ptr,
                                                      int* __restrict__ cursor,
                                                      int* __restrict__ edge_src,
                                                      int N) {
    int b = blockIdx.x;
    int lo = b << 8;
    int hiN = min((b + 1) << 8, N);
    int gstart = row_ptr[lo];
    int gend   = row_ptr[hiN];
    for (int p = gstart + threadIdx.x; p < gend; p += 256) {
        long long pr = __builtin_nontemporal_load(&staged[p]);
        int d = (int)(pr >> 32);
        int s = (int)(pr & 0xFFFFFFFFll);
        int pos = atomicAdd(&cursor[d], 1);
        edge_src[pos] = s;
    }
}

// ---------------------------------------------------------------------------
// Weight pre-pack (6 matrices) MERGED with degree histogram: blocks 0..27 pack,
// blocks 28.. histogram (independent work; deg is zeroed by the prior memset).
// ---------------------------------------------------------------------------
__global__ __launch_bounds__(256) void pack_hist(
        const float* __restrict__ W0, const float* __restrict__ W1,
        const float* __restrict__ W2, const float* __restrict__ W3,
        const float* __restrict__ W4, const float* __restrict__ W5,
        ushort_t* H0, ushort_t* L0, ushort_t* H1, ushort_t* L1,
        ushort_t* H2, ushort_t* L2, ushort_t* H3, ushort_t* L3,
        ushort_t* H4, ushort_t* L4, ushort_t* H5, ushort_t* L5,
        const int* __restrict__ dst, int* __restrict__ deg, int E) {
    int b = blockIdx.x;
    if (b >= 28) {
        int e = (b - 28) * 256 + threadIdx.x;
        if (e < E) atomicAdd(&deg[__builtin_nontemporal_load(&dst[e])], 1);
        return;
    }
    const float* W; ushort_t* Hi; ushort_t* Lo; int K, NS, base;
    if (b < 8)       { W = W0; Hi = H0; Lo = L0; K = 128; NS = 128; base = 0;  }
    else if (b < 16) { W = W1; Hi = H1; Lo = L1; K = 128; NS = 128; base = 8;  }
    else if (b < 20) { W = W2; Hi = H2; Lo = L2; K = 128; NS = 64;  base = 16; }
    else if (b < 24) { W = W3; Hi = H3; Lo = L3; K = 128; NS = 64;  base = 20; }
    else if (b < 26) { W = W4; Hi = H4; Lo = L4; K = 64;  NS = 64;  base = 24; }
    else             { W = W5; Hi = H5; Lo = L5; K = 64;  NS = 64;  base = 26; }
    int tid = (b - base) * 256 + threadIdx.x;
    if (tid >= (K * NS) / 8) return;
    int l  = tid & 63;
    int fl = tid >> 6;
    int NT = NS / 16;
    int t = fl % NT, s = fl / NT;
    ushort_t hs[8], ls[8];
    #pragma unroll
    for (int j = 0; j < 8; ++j) {
        int k = s * 32 + (l >> 4) * 8 + j;
        int n = t * 16 + (l & 15);
        float w = W[(size_t)k * NS + n];
        ushort_t h = f2bf(w);
        hs[j] = h;
        ls[j] = f2bf(w - bf2f(h));
    }
    #pragma unroll
    for (int j = 0; j < 8; ++j) {
        Hi[(size_t)tid * 8 + j] = hs[j];
        Lo[(size_t)tid * 8 + j] = ls[j];
    }
}

// ---------------------------------------------------------------------------
// MFMA dual GEMM (split-bf16, fp32-grade) with LDS-transposed vector epilogue:
//   S[M,NS]  = X @ Ws + bias  (fp32 out, float4 stores)
//   Zb[M,NS] = X @ Wn         (bf16 out, uint2 stores)
// Per-wave private LDS staging (stride 20 words -> max 2-way bank alias, free;
// no barriers needed).
// ---------------------------------------------------------------------------
template <int K, int NS>
__global__ __launch_bounds__(256) void mfma_gemm(const float* __restrict__ X,
                                                 const ushort_t* __restrict__ BsHi,
                                                 const ushort_t* __restrict__ BsLo,
                                                 const ushort_t* __restrict__ BnHi,
                                                 const ushort_t* __restrict__ BnLo,
                                                 const float* __restrict__ bias,
                                                 float* __restrict__ S,
                                                 ushort_t* __restrict__ Zb,
                                                 int M) {
    constexpr int KS = K / 32;      // mfma k-steps
    constexpr int NT = NS / 16;     // n-tiles
    __shared__ float ldsS[4][32 * 20];   // per-wave private transpose buffers
    __shared__ float ldsZ[4][32 * 20];
    int tid = threadIdx.x;
    int lane = tid & 63, w = tid >> 6;
    int baseM = blockIdx.x * 128 + w * 32;
    int rIn = lane & 15, q = lane >> 4;
    float* bufS = ldsS[w];
    float* bufZ = ldsZ[w];

    // ---- load + split all A fragments for this wave's 32 rows ----
    short8 Ahi[KS][2], Alo[KS][2];
    #pragma unroll
    for (int s = 0; s < KS; ++s) {
        #pragma unroll
        for (int mt = 0; mt < 2; ++mt) {
            int gm = baseM + mt * 16 + rIn;
            if (gm < M) {
                split8(&X[(size_t)gm * K + s * 32 + q * 8], Ahi[s][mt], Alo[s][mt]);
            } else {
                #pragma unroll
                for (int j = 0; j < 8; ++j) { Ahi[s][mt][j] = 0; Alo[s][mt][j] = 0; }
            }
        }
    }

    // ---- loop n-tiles; stream B frags from L2; 12 MFMA per (s,t) ----
    for (int t = 0; t < NT; ++t) {
        f32x4 aS0 = {0.f, 0.f, 0.f, 0.f}, aS1 = {0.f, 0.f, 0.f, 0.f};
        f32x4 aZ0 = {0.f, 0.f, 0.f, 0.f}, aZ1 = {0.f, 0.f, 0.f, 0.f};
        #pragma unroll
        for (int s = 0; s < KS; ++s) {
            size_t fo = ((size_t)(s * NT + t) * 64 + lane) * 8;
            short8 bsh = *(const short8*)&BsHi[fo];
            short8 bsl = *(const short8*)&BsLo[fo];
            short8 bnh = *(const short8*)&BnHi[fo];
            short8 bnl = *(const short8*)&BnLo[fo];
            aS0 = __builtin_amdgcn_mfma_f32_16x16x32_bf16(Ahi[s][0], bsh, aS0, 0, 0, 0);
            aS0 = __builtin_amdgcn_mfma_f32_16x16x32_bf16(Alo[s][0], bsh, aS0, 0, 0, 0);
            aS0 = __builtin_amdgcn_mfma_f32_16x16x32_bf16(Ahi[s][0], bsl, aS0, 0, 0, 0);
            aS1 = __builtin_amdgcn_mfma_f32_16x16x32_bf16(Ahi[s][1], bsh, aS1, 0, 0, 0);
            aS1 = __builtin_amdgcn_mfma_f32_16x16x32_bf16(Alo[s][1], bsh, aS1, 0, 0, 0);
            aS1 = __builtin_amdgcn_mfma_f32_16x16x32_bf16(Ahi[s][1], bsl, aS1, 0, 0, 0);
            aZ0 = __builtin_amdgcn_mfma_f32_16x16x32_bf16(Ahi[s][0], bnh, aZ0, 0, 0, 0);
            aZ0 = __builtin_amdgcn_mfma_f32_16x16x32_bf16(Alo[s][0], bnh, aZ0, 0, 0, 0);
            aZ0 = __builtin_amdgcn_mfma_f32_16x16x32_bf16(Ahi[s][0], bnl, aZ0, 0, 0, 0);
            aZ1 = __builtin_amdgcn_mfma_f32_16x16x32_bf16(Ahi[s][1], bnh, aZ1, 0, 0, 0);
            aZ1 = __builtin_amdgcn_mfma_f32_16x16x32_bf16(Alo[s][1], bnh, aZ1, 0, 0, 0);
            aZ1 = __builtin_amdgcn_mfma_f32_16x16x32_bf16(Ahi[s][1], bnl, aZ1, 0, 0, 0);
        }
        // ---- epilogue: C layout (col=rIn, row=q*4+r) -> LDS -> float4 stores
        #pragma unroll
        for (int r = 0; r < 4; ++r) {
            bufS[(q * 4 + r) * 20 + rIn]        = aS0[r];
            bufS[(16 + q * 4 + r) * 20 + rIn]   = aS1[r];
            bufZ[(q * 4 + r) * 20 + rIn]        = aZ0[r];
            bufZ[(16 + q * 4 + r) * 20 + rIn]   = aZ1[r];
        }
        int row = lane >> 2;            // 0..15
        int cq  = lane & 3;
        int col = t * 16 + cq * 4;
        float4 bv = *(const float4*)&bias[col];
        #pragma unroll
        for (int half = 0; half < 2; ++half) {
            int gm = baseM + half * 16 + row;
            float4 v = *(float4*)&bufS[(half * 16 + row) * 20 + cq * 4];
            float4 z = *(float4*)&bufZ[(half * 16 + row) * 20 + cq * 4];
            if (gm < M) {
                float4 o;
                o.x = v.x + bv.x; o.y = v.y + bv.y;
                o.z = v.z + bv.z; o.w = v.w + bv.w;
                *(float4*)&S[(size_t)gm * NS + col] = o;
                uint2 o2;
                o2.x = (unsigned)f2bf(z.x) | ((unsigned)f2bf(z.y) << 16);
                o2.y = (unsigned)f2bf(z.z) | ((unsigned)f2bf(z.w) << 16);
                *(uint2*)&Zb[(size_t)gm * NS + col] = o2;
            }
        }
    }
}

// ---------------------------------------------------------------------------
// Aggregate with bf16 Z: out[n,f] = act( S[n,f] + inv_deg[n]*sum Z[src,f] )
// G = D/8 lanes per node (16 for D=128, 8 for D=64); every lane gathers 16B
// (uint4). Edge indices loaded cooperatively + shfl broadcast. S/invd hoisted.
// ACT: 0 = relu, 1 = softmax across the 8-lane group (D=64 only)
// (Verified at the random-gather pattern floor in R0-R3: ~3.8 TB/s, ~205 MB.)
// ---------------------------------------------------------------------------
template <int D, int ACT>
__global__ __launch_bounds__(256) void agg_kernel(const float* __restrict__ S,
                                                  const ushort_t* __restrict__ Zb,
                                                  const int* __restrict__ row_ptr,
                                                  const int* __restrict__ edge_src,
                                                  const float* __restrict__ inv_deg,
                                                  float* __restrict__ out, int N) {
    constexpr int G  = D / 8;          // lanes per node: 16 (D=128) / 8 (D=64)
    constexpr int PF = 8;              // floats per lane (both widths)
    constexpr int NG = 256 / G;        // nodes per block: 16 / 32
    constexpr int U  = G;              // edges per batch = lanes per group
    int tid = threadIdx.x;
    int g = tid / G, fl = tid % G;
    int n = blockIdx.x * NG + g;
    if (n >= N) return;
    int beg = row_ptr[n], end = row_ptr[n + 1];
    float id = inv_deg[n];

    // hoisted stream loads (overlap with gathers)
    const f32x4* Sp = (const f32x4*)(S + (size_t)n * D) + fl * 2;
    f32x4 s40 = __builtin_nontemporal_load(Sp);
    f32x4 s41 = __builtin_nontemporal_load(Sp + 1);

    float acc[2][PF];
    #pragma unroll
    for (int i = 0; i < PF; ++i) { acc[0][i] = 0.f; acc[1][i] = 0.f; }

    const char* zlane = (const char*)Zb + fl * 16;   // 16B per lane within row

    for (int j = beg; j < end; j += U) {
        int je = j + fl;
        int myS = (je < end) ? __builtin_nontemporal_load(&edge_src[je]) : -1;
        uint4 u[U];
        #pragma unroll
        for (int k = 0; k < U; ++k) {
            int s = __shfl(myS, k, U);   // broadcast within the G-lane group
            u[k] = make_uint4(0u, 0u, 0u, 0u);
            if (s >= 0)
                u[k] = *(const uint4*)(zlane + ((size_t)((unsigned)s) * (D * 2)));
        }
        #pragma unroll
        for (int k = 0; k < U; ++k) {
            acc_u32(u[k].x, acc[k & 1][0], acc[k & 1][1]);
            acc_u32(u[k].y, acc[k & 1][2], acc[k & 1][3]);
            acc_u32(u[k].z, acc[k & 1][4], acc[k & 1][5]);
            acc_u32(u[k].w, acc[k & 1][6], acc[k & 1][7]);
        }
    }

    float v[PF];
    #pragma unroll
    for (int i = 0; i < 4; ++i) {
        v[i]     = s40[i] + id * (acc[0][i]     + acc[1][i]);
        v[4 + i] = s41[i] + id * (acc[0][4 + i] + acc[1][4 + i]);
    }

    float4* Op = (float4*)(out + (size_t)n * D) + fl * 2;
    if constexpr (ACT == 0) {
        float4 o0, o1;
        o0.x = fmaxf(v[0], 0.f); o0.y = fmaxf(v[1], 0.f);
        o0.z = fmaxf(v[2], 0.f); o0.w = fmaxf(v[3], 0.f);
        o1.x = fmaxf(v[4], 0.f); o1.y = fmaxf(v[5], 0.f);
        o1.z = fmaxf(v[6], 0.f); o1.w = fmaxf(v[7], 0.f);
        Op[0] = o0; Op[1] = o1;
    } else {
        // softmax across 8 lanes x 8 vals (D == 64)
        float m = v[0];
        #pragma unroll
        for (int i = 1; i < 8; ++i) m = fmaxf(m, v[i]);
        #pragma unroll
        for (int off = 4; off > 0; off >>= 1) m = fmaxf(m, __shfl_xor(m, off, 8));
        float e[8], s = 0.f;
        #pragma unroll
        for (int i = 0; i < 8; ++i) { e[i] = __expf(v[i] - m); s += e[i]; }
        #pragma unroll
        for (int off = 4; off > 0; off >>= 1) s += __shfl_xor(s, off, 8);
        float inv = 1.0f / s;
        float4 o0, o1;
        o0.x = e[0] * inv; o0.y = e[1] * inv; o0.z = e[2] * inv; o0.w = e[3] * inv;
        o1.x = e[4] * inv; o1.y = e[5] * inv; o1.z = e[6] * inv; o1.w = e[7] * inv;
        Op[0] = o0; Op[1] = o1;
    }
}

// ---------------------------------------------------------------------------
extern "C" void kernel_launch(void* const* d_in, const int* in_sizes, int n_in,
                              void* d_out, int out_size, void* d_ws, size_t ws_size,
                              hipStream_t stream) {
    const float* in_feat = (const float*)d_in[0];
    const int*   src     = (const int*)d_in[1];
    const int*   dst     = (const int*)d_in[2];
    const float* w1s = (const float*)d_in[3];
    const float* w1n = (const float*)d_in[4];
    const float* b1  = (const float*)d_in[5];
    const float* w2s = (const float*)d_in[6];
    const float* w2n = (const float*)d_in[7];
    const float* b2  = (const float*)d_in[8];
    const float* w3s = (const float*)d_in[9];
    const float* w3n = (const float*)d_in[10];
    const float* b3  = (const float*)d_in[11];

    const int N = N_NODES;
    const int E = in_sizes[1];

    char* p = (char*)d_ws;
    auto carve = [&](size_t bytes) -> char* {
        char* q = p;
        p += (bytes + 511) & ~(size_t)511;
        return q;
    };
    float*    S        = (float*)   carve((size_t)N * 128 * sizeof(float));
    ushort_t* Zb       = (ushort_t*)carve((size_t)N * 128 * sizeof(ushort_t));
    float*    H        = (float*)   carve((size_t)N * 128 * sizeof(float));
    int*      edge_src = (int*)     carve((size_t)E * sizeof(int));
    int*      row_ptr  = (int*)     carve((size_t)(N + 1) * sizeof(int));
    int*      cursor   = (int*)     carve((size_t)N * sizeof(int));
    int*      deg      = (int*)     carve((size_t)N * sizeof(int));
    float*    invd     = (float*)   carve((size_t)N * sizeof(float));
    int*      partials = (int*)     carve(256 * sizeof(int));
    int*      gcur     = (int*)     carve(MAXBUCK * sizeof(int));
    // staging pairs alias H (H is only written after scatter completes)
    long long* staged  = (long long*)H;
    // packed weights (hi/lo per matrix)
    ushort_t* P1sH = (ushort_t*)carve(128 * 128 * 2); ushort_t* P1sL = (ushort_t*)carve(128 * 128 * 2);
    ushort_t* P1nH = (ushort_t*)carve(128 * 128 * 2); ushort_t* P1nL = (ushort_t*)carve(128 * 128 * 2);
    ushort_t* P2sH = (ushort_t*)carve(128 * 64 * 2);  ushort_t* P2sL = (ushort_t*)carve(128 * 64 * 2);
    ushort_t* P2nH = (ushort_t*)carve(128 * 64 * 2);  ushort_t* P2nL = (ushort_t*)carve(128 * 64 * 2);
    ushort_t* P3sH = (ushort_t*)carve(64 * 64 * 2);   ushort_t* P3sL = (ushort_t*)carve(64 * 64 * 2);
    ushort_t* P3nH = (ushort_t*)carve(64 * 64 * 2);   ushort_t* P3nL = (ushort_t*)carve(64 * 64 * 2);

    // ---- CSR build + weight packing (pack fused into hist launch) ----
    (void)hipMemsetAsync(deg, 0, (size_t)N * sizeof(int), stream);
    pack_hist<<<28 + (E + 255) / 256, 256, 0, stream>>>(
        w1s, w1n, w2s, w2n, w3s, w3n,
        P1sH, P1sL, P1nH, P1nL,
        P2sH, P2sL, P2nH, P2nL,
        P3sH, P3sL, P3nH, P3nL,
        dst, deg, E);
    const int NB = (N + 1023) / 1024;   // 98 segments
    scan_partial_sums<<<NB, 256, 0, stream>>>(deg, partials, N);
    scan_partials<<<1, 256, 0, stream>>>(partials, NB, row_ptr, N);
    scan_emit<<<NB, 256, 0, stream>>>(deg, partials, row_ptr, cursor, invd, gcur, N);
    const int NBUCK = (N + 255) >> 8;          // 391 buckets of 256 nodes
    const int BINB  = 256;
    const int CHUNK = (E + BINB - 1) / BINB;
    bin_pairs<<<BINB, 256, 0, stream>>>(src, dst, gcur, staged, E, NBUCK, CHUNK);
    scatter_bucket<<<NBUCK, 256, 0, stream>>>(staged, row_ptr, cursor, edge_src, N);

    const int GB   = (N + 127) / 128;   // 782 row blocks
    const int AB128 = (N + 15) / 16;    // agg blocks, D=128: 16 nodes each
    const int AB64  = (N + 31) / 32;    // agg blocks, D=64:  32 nodes each

    // ---- Layer 1: 128 -> 128, relu ----
    mfma_gemm<128, 128><<<GB, 256, 0, stream>>>(in_feat, P1sH, P1sL, P1nH, P1nL, b1, S, Zb, N);
    agg_kernel<128, 0><<<AB128, 256, 0, stream>>>(S, Zb, row_ptr, edge_src, invd, H, N);

    // ---- Layer 2: 128 -> 64, relu ----
    mfma_gemm<128, 64><<<GB, 256, 0, stream>>>(H, P2sH, P2sL, P2nH, P2nL, b2, S, Zb, N);
    agg_kernel<64, 0><<<AB64, 256, 0, stream>>>(S, Zb, row_ptr, edge_src, invd, H, N);

    // ---- Layer 3: 64 -> 64, softmax ----
    mfma_gemm<64, 64><<<GB, 256, 0, stream>>>(H, P3sH, P3sL, P3nH, P3nL, b3, S, Zb, N);
    agg_kernel<64, 1><<<AB64, 256, 0, stream>>>(S, Zb, row_ptr, edge_src, invd,
                                                (float*)d_out, N);
}